// Round 2
// baseline (299.587 us; speedup 1.0000x reference)
//
#include <hip/hip_runtime.h>

// Problem constants (fixed by the reference):
//   B=32, C=256, H=64, W=64.  Positions = B*H*W = 131072.
//   Pure streaming reduction: 268.9 MB read once.
//   L3 (256 MiB) retains ~half the inputs across iterations (measured
//   FETCH_SIZE = 134.5 MB = half) -> floor ~30-40 us.
//
// v3 theory: v2 measured 99.5 us kernel, VGPR_Count=32, VALUBusy=2.5%,
//   HBM 1.35 TB/s. The compiler collapsed the unrolled loop into
//   load-pair -> waitcnt -> fma (32 VGPRs can't even hold one 8-channel
//   batch), leaving ~2 loads in flight per wave => latency-bound.
// Fix: explicit float4[8] register arrays so 16 global_load_dwordx4 are
//   issued back-to-back before consumption (16 KB/wave in flight,
//   ~96-110 VGPR, still 16 waves/CU).  Also fuse the finalize into the
//   main kernel (last-block-done counter) -> 2 dispatches, not 3.

#define BB   32
#define CC   256
#define HH   64
#define WW   64
#define HWSZ (HH * WW)            // 4096 floats per (b,c) plane
#define NPOS (BB * HWSZ)          // 131072 positions
#define HW4  (HWSZ / 4)           // 1024 float4 per plane
#define PPB  256                  // positions per block
#define NW   8                    // waves per block (512 threads)
#define CPW  (CC / NW)            // 32 channels per wave
#define NB   8                    // channels per load batch
#define NG   (CPW / NB)           // 4 batches
#define NBLK (NPOS / PPB)         // 512 blocks
#define SIM_EPS 1e-8f

__global__ __launch_bounds__(512) void
sim_reduce_kernel(const float4* __restrict__ u4,
                  const float4* __restrict__ m4,
                  const int*    __restrict__ mask,
                  double*       __restrict__ ws,
                  float*        __restrict__ out)
{
    // Per-wave channel-chunk partials for the block's 256 positions.
    __shared__ float4 s_num[NW][64];
    __shared__ float4 s_uu [NW][64];
    __shared__ float4 s_mm [NW][64];

    const int wv = threadIdx.x >> 6;     // wave id: which 32-channel chunk
    const int l  = threadIdx.x & 63;     // lane: which float4 group of positions

    const int pos0 = blockIdx.x * PPB;   // block's first position
    const int b    = pos0 >> 12;         // pos0 / 4096 (PPB divides HWSZ)
    const int hw0  = pos0 & (HWSZ - 1);

    // float4 index of this thread's 4 positions at its first channel.
    const size_t base4 = (size_t)b * CC * HW4
                       + (size_t)(wv * CPW) * HW4
                       + (size_t)(hw0 >> 2) + (size_t)l;
    const float4* __restrict__ up = u4 + base4;
    const float4* __restrict__ mp = m4 + base4;

    float4 num = make_float4(0.f, 0.f, 0.f, 0.f);
    float4 uu  = make_float4(0.f, 0.f, 0.f, 0.f);
    float4 mm  = make_float4(0.f, 0.f, 0.f, 0.f);

    // Batched loads: 16 global_load_dwordx4 issued before any FMA consumes
    // them.  Named arrays, fully unrolled -> all lifetimes overlap -> the
    // compiler must keep them resident (defeats the 32-VGPR collapse seen
    // in v2) and can retire FMAs with counted vmcnt waits.
#pragma unroll
    for (int g = 0; g < NG; ++g) {
        float4 av[NB];
        float4 bv[NB];
#pragma unroll
        for (int j = 0; j < NB; ++j) {
            av[j] = up[(size_t)(g * NB + j) * HW4];
            bv[j] = mp[(size_t)(g * NB + j) * HW4];
        }
#pragma unroll
        for (int j = 0; j < NB; ++j) {
            num.x = fmaf(av[j].x, bv[j].x, num.x);
            num.y = fmaf(av[j].y, bv[j].y, num.y);
            num.z = fmaf(av[j].z, bv[j].z, num.z);
            num.w = fmaf(av[j].w, bv[j].w, num.w);
            uu.x  = fmaf(av[j].x, av[j].x, uu.x);
            uu.y  = fmaf(av[j].y, av[j].y, uu.y);
            uu.z  = fmaf(av[j].z, av[j].z, uu.z);
            uu.w  = fmaf(av[j].w, av[j].w, uu.w);
            mm.x  = fmaf(bv[j].x, bv[j].x, mm.x);
            mm.y  = fmaf(bv[j].y, bv[j].y, mm.y);
            mm.z  = fmaf(bv[j].z, bv[j].z, mm.z);
            mm.w  = fmaf(bv[j].w, bv[j].w, mm.w);
        }
    }

    s_num[wv][l] = num;
    s_uu [wv][l] = uu;
    s_mm [wv][l] = mm;
    __syncthreads();

    // Phase 2: first 4 waves combine the 8 channel-chunk partials per
    // position, compute cosine sim, apply mask.
    double sd = 0.0, md = 0.0;
    if (threadIdx.x < PPB) {
        const int t = threadIdx.x;
        float fn = 0.f, fu = 0.f, fm = 0.f;
#pragma unroll
        for (int k = 0; k < NW; ++k) {
            fn += ((const float*)s_num[k])[t];
            fu += ((const float*)s_uu [k])[t];
            fm += ((const float*)s_mm [k])[t];
        }
        const float denom = fmaxf(sqrtf(fu), SIM_EPS) * fmaxf(sqrtf(fm), SIM_EPS);
        const float sim   = fn / denom;
        if (mask[pos0 + t] != 0) { sd = (double)sim; md = 1.0; }
    }

    // Block reduction: wave shfl (inactive waves contribute 0) -> LDS.
#pragma unroll
    for (int off = 32; off > 0; off >>= 1) {
        sd += __shfl_down(sd, off, 64);
        md += __shfl_down(md, off, 64);
    }

    __shared__ double r_s[NW];
    __shared__ double r_m[NW];
    if (l == 0) { r_s[wv] = sd; r_m[wv] = md; }
    __syncthreads();

    if (threadIdx.x == 0) {
        double ts = 0.0, tm = 0.0;
#pragma unroll
        for (int k = 0; k < NW; ++k) { ts += r_s[k]; tm += r_m[k]; }
        atomicAdd(&ws[0], ts);   // device-scope by default on CDNA
        atomicAdd(&ws[1], tm);
        __threadfence();         // make our adds visible before the ticket
        const unsigned long long prev =
            atomicAdd((unsigned long long*)&ws[2], 1ull);
        if (prev == (unsigned long long)(NBLK - 1)) {
            // Last block: every other block has fenced its adds before
            // incrementing the ticket.  Read via atomicAdd(+0.0) to get
            // coherent device-scope values (bypasses any stale L1).
            const double s  = atomicAdd(&ws[0], 0.0);
            const double mc = atomicAdd(&ws[1], 0.0);
            out[0] = (float)(s / mc);
        }
    }
}

extern "C" void kernel_launch(void* const* d_in, const int* in_sizes, int n_in,
                              void* d_out, int out_size, void* d_ws, size_t ws_size,
                              hipStream_t stream)
{
    const float4* u4   = (const float4*)d_in[0];
    const float4* m4   = (const float4*)d_in[1];
    const int*    mask = (const int*)d_in[2];
    float*  out = (float*)d_out;
    double* ws  = (double*)d_ws;

    // ws is re-poisoned before every timed launch -> zero the two
    // accumulators + the completion ticket on-stream (graph-capture safe).
    hipMemsetAsync(d_ws, 0, 3 * sizeof(double), stream);

    sim_reduce_kernel<<<NBLK, 512, 0, stream>>>(u4, m4, mask, ws, out);
}

// Round 3
// 296.564 us; speedup vs baseline: 1.0102x; 1.0102x over previous
//
#include <hip/hip_runtime.h>

// Problem constants (fixed by the reference):
//   B=32, C=256, H=64, W=64.  Positions = B*H*W = 131072.
//   Pure streaming reduction: 268.9 MB read once; L3 retains ~half
//   (measured FETCH_SIZE = 134.5 MB) -> floor ~25-35 us.
//
// History:
//   v2 (8 waves/block, pair loads, unroll 4):   kernel 99.5 us, VGPR 32, occ 37%
//   v3 (explicit 16-load batches):              kernel 124 us, VGPR 64  <- REGRESSION
//     post-mortem: compiler turned batches into burst+vmcnt(0)+stall;
//     source-level pipelining is defeated (cf. m131-m141).  Reverted.
//
// v4 theory: VALUBusy 2%, conflicts 0, occupancy only 33-39% with a
//   16-waves/CU ceiling (512 blocks x 8 waves on 256 CUs) => latency-bound
//   on aggregate in-flight bytes, which scale with resident waves.
// Fix: 16-way channel split, block = 1024 threads (16 waves) -> same 512
//   blocks now allow 32 waves/CU (100% occupancy ceiling).  LDS 49 KB/block
//   (2 blocks/CU = 98 KB < 160 KB).  Keep v2's pipelined pair loop.

#define BB   32
#define CC   256
#define HH   64
#define WW   64
#define HWSZ (HH * WW)            // 4096 floats per (b,c) plane
#define NPOS (BB * HWSZ)          // 131072 positions
#define HW4  (HWSZ / 4)           // 1024 float4 per plane
#define PPB  256                  // positions per block
#define NW   16                   // waves per block (1024 threads)
#define CPW  (CC / NW)            // 16 channels per wave
#define NBLK (NPOS / PPB)         // 512 blocks
#define SIM_EPS 1e-8f

__global__ __launch_bounds__(1024) void
sim_reduce_kernel(const float4* __restrict__ u4,
                  const float4* __restrict__ m4,
                  const int*    __restrict__ mask,
                  double*       __restrict__ ws,
                  float*        __restrict__ out)
{
    // Per-wave channel-chunk partials for the block's 256 positions.
    // float4 writes (conflict-free ds_write_b128), scalar stride-1 reads.
    __shared__ float4 s_num[NW][64];
    __shared__ float4 s_uu [NW][64];
    __shared__ float4 s_mm [NW][64];

    const int wv = threadIdx.x >> 6;     // wave id: which 16-channel chunk
    const int l  = threadIdx.x & 63;     // lane: which float4 group of positions

    const int pos0 = blockIdx.x * PPB;   // block's first position
    const int b    = pos0 >> 12;         // pos0 / 4096 (PPB divides HWSZ)
    const int hw0  = pos0 & (HWSZ - 1);

    // Prefetch this thread's mask value (used in phase 2) so the load
    // overlaps the main loop instead of serializing at the end.
    int mk = 0;
    if (threadIdx.x < PPB) mk = mask[pos0 + threadIdx.x];

    // float4 index of this thread's 4 positions at its first channel.
    const size_t base4 = (size_t)b * CC * HW4
                       + (size_t)(wv * CPW) * HW4
                       + (size_t)(hw0 >> 2) + (size_t)l;
    const float4* __restrict__ up = u4 + base4;
    const float4* __restrict__ mp = m4 + base4;

    float4 num = make_float4(0.f, 0.f, 0.f, 0.f);
    float4 uu  = make_float4(0.f, 0.f, 0.f, 0.f);
    float4 mm  = make_float4(0.f, 0.f, 0.f, 0.f);

    // v2-style pipelined pair loads (empirically the best-scheduled form).
#pragma unroll 4
    for (int c = 0; c < CPW; ++c) {
        const float4 a  = up[(size_t)c * HW4];
        const float4 bv = mp[(size_t)c * HW4];
        num.x = fmaf(a.x, bv.x, num.x);
        num.y = fmaf(a.y, bv.y, num.y);
        num.z = fmaf(a.z, bv.z, num.z);
        num.w = fmaf(a.w, bv.w, num.w);
        uu.x  = fmaf(a.x, a.x,  uu.x);
        uu.y  = fmaf(a.y, a.y,  uu.y);
        uu.z  = fmaf(a.z, a.z,  uu.z);
        uu.w  = fmaf(a.w, a.w,  uu.w);
        mm.x  = fmaf(bv.x, bv.x, mm.x);
        mm.y  = fmaf(bv.y, bv.y, mm.y);
        mm.z  = fmaf(bv.z, bv.z, mm.z);
        mm.w  = fmaf(bv.w, bv.w, mm.w);
    }

    s_num[wv][l] = num;
    s_uu [wv][l] = uu;
    s_mm [wv][l] = mm;
    __syncthreads();

    // Phase 2: first 4 waves combine the 16 channel-chunk partials per
    // position, compute cosine sim, apply mask.
    double sd = 0.0, md = 0.0;
    if (threadIdx.x < PPB) {
        const int t = threadIdx.x;
        float fn = 0.f, fu = 0.f, fm = 0.f;
#pragma unroll
        for (int k = 0; k < NW; ++k) {
            fn += ((const float*)s_num[k])[t];
            fu += ((const float*)s_uu [k])[t];
            fm += ((const float*)s_mm [k])[t];
        }
        const float denom = fmaxf(sqrtf(fu), SIM_EPS) * fmaxf(sqrtf(fm), SIM_EPS);
        const float sim   = fn / denom;
        if (mk != 0) { sd = (double)sim; md = 1.0; }
    }

    // Block reduction: wave shfl (inactive waves contribute 0) -> LDS.
#pragma unroll
    for (int off = 32; off > 0; off >>= 1) {
        sd += __shfl_down(sd, off, 64);
        md += __shfl_down(md, off, 64);
    }

    __shared__ double r_s[NW];
    __shared__ double r_m[NW];
    if (l == 0) { r_s[wv] = sd; r_m[wv] = md; }
    __syncthreads();

    if (threadIdx.x == 0) {
        double ts = 0.0, tm = 0.0;
#pragma unroll
        for (int k = 0; k < NW; ++k) { ts += r_s[k]; tm += r_m[k]; }
        atomicAdd(&ws[0], ts);   // device-scope by default on CDNA
        atomicAdd(&ws[1], tm);
        __threadfence();         // make our adds visible before the ticket
        const unsigned long long prev =
            atomicAdd((unsigned long long*)&ws[2], 1ull);
        if (prev == (unsigned long long)(NBLK - 1)) {
            // Last block: every other block fenced its adds before the
            // ticket increment.  atomicAdd(+0.0) reads are device-coherent.
            const double s  = atomicAdd(&ws[0], 0.0);
            const double mc = atomicAdd(&ws[1], 0.0);
            out[0] = (float)(s / mc);
        }
    }
}

extern "C" void kernel_launch(void* const* d_in, const int* in_sizes, int n_in,
                              void* d_out, int out_size, void* d_ws, size_t ws_size,
                              hipStream_t stream)
{
    const float4* u4   = (const float4*)d_in[0];
    const float4* m4   = (const float4*)d_in[1];
    const int*    mask = (const int*)d_in[2];
    float*  out = (float*)d_out;
    double* ws  = (double*)d_ws;

    // ws is re-poisoned before every timed launch -> zero the two
    // accumulators + the completion ticket on-stream (graph-capture safe).
    hipMemsetAsync(d_ws, 0, 3 * sizeof(double), stream);

    sim_reduce_kernel<<<NBLK, 1024, 0, stream>>>(u4, m4, mask, ws, out);
}

// Round 4
// 294.014 us; speedup vs baseline: 1.0190x; 1.0087x over previous
//
#include <hip/hip_runtime.h>

// Problem: B=32, C=256, H=64, W=64.  Positions = 131072.  269 MB streamed.
//
// History:
//   v2 (8 waves/blk, strided pair loads):  99.5 us, HBM 1.35 TB/s
//   v3 (explicit load batches):           124 us  REGRESSION (compiler burst+drain)
//   v4 (16 waves/blk, occ 35->65%):       119 us  BW UNCHANGED -> occupancy not the limiter
//
// v5 theory: all prior versions walk memory as 1 KB granules at a 16 KB
//   power-of-2 stride (channel stride).  Total service rate pins at
//   2.26 TB/s regardless of waves/ILP => DRAM row-buffer / bank-alias
//   thrash (copy ubench with contiguous walk: 6.29 TB/s).  Fix the ADDRESS
//   ORDER: phase A gives each block a contiguous 256 KB chunk (b, 16
//   channels) streamed linearly with register accumulators per position;
//   per-chunk partials stored (25 MB ws, no atomics); phase B combines 16
//   chunks/position, cosine+mask, reduce, fused finalize.

#define BB    32
#define CC    256
#define HWSZ  4096                 // H*W floats per plane
#define NPOS  (BB * HWSZ)          // 131072
#define HW4   (HWSZ / 4)           // 1024 float4 per plane
#define NP4   (NPOS / 4)           // 32768 float4 position-groups
#define CHUNK 16                   // channels per phase-A block
#define NCH   (CC / CHUNK)         // 16 chunks
#define NBLK_A (BB * NCH)          // 512 blocks
#define THR_A  512
#define THR_B  512
#define NBLK_B (NP4 / THR_B)       // 64 blocks
#define SIM_EPS 1e-8f

// ws layout: float4 partial[ch][comp][p4]  (comp: 0=num,1=uu,2=mm)
//            then 64 B tail of doubles {sum_sim, sum_mask, ticket}.
#define WS_PART_F4 (NCH * 3 * NP4)                    // 1,572,864 float4
#define WS_NEED    ((size_t)WS_PART_F4 * 16 + 64)

// ---------------- Phase A: contiguous streaming, per-chunk partials -------
__global__ __launch_bounds__(THR_A) void
partial_kernel(const float4* __restrict__ u4,
               const float4* __restrict__ m4,
               float4* __restrict__ wsp)
{
    const int blk = blockIdx.x;
    const int b   = blk >> 4;               // / NCH
    const int ch  = blk & (NCH - 1);
    const int tid = threadIdx.x;

    // Block's contiguous 256 KB region: channels [ch*16, ch*16+16) of batch b.
    const size_t base4 = ((size_t)b * CC + (size_t)ch * CHUNK) * HW4;
    const float4* __restrict__ up = u4 + base4 + tid;
    const float4* __restrict__ mp = m4 + base4 + tid;

    // Register partials for this thread's 8 fixed positions:
    //   j=0: hw4 = tid, j=1: hw4 = tid+512 (same offsets in every plane).
    float4 n0 = make_float4(0.f,0.f,0.f,0.f), n1 = n0;
    float4 s0 = n0, s1 = n0;                 // uu
    float4 t0 = n0, t1 = n0;                 // mm

#pragma unroll 2
    for (int cc = 0; cc < CHUNK; ++cc) {
        const size_t o = (size_t)cc * HW4;
        const float4 a0 = up[o];
        const float4 b0 = mp[o];
        const float4 a1 = up[o + 512];
        const float4 b1 = mp[o + 512];

        n0.x = fmaf(a0.x, b0.x, n0.x); n0.y = fmaf(a0.y, b0.y, n0.y);
        n0.z = fmaf(a0.z, b0.z, n0.z); n0.w = fmaf(a0.w, b0.w, n0.w);
        s0.x = fmaf(a0.x, a0.x, s0.x); s0.y = fmaf(a0.y, a0.y, s0.y);
        s0.z = fmaf(a0.z, a0.z, s0.z); s0.w = fmaf(a0.w, a0.w, s0.w);
        t0.x = fmaf(b0.x, b0.x, t0.x); t0.y = fmaf(b0.y, b0.y, t0.y);
        t0.z = fmaf(b0.z, b0.z, t0.z); t0.w = fmaf(b0.w, b0.w, t0.w);

        n1.x = fmaf(a1.x, b1.x, n1.x); n1.y = fmaf(a1.y, b1.y, n1.y);
        n1.z = fmaf(a1.z, b1.z, n1.z); n1.w = fmaf(a1.w, b1.w, n1.w);
        s1.x = fmaf(a1.x, a1.x, s1.x); s1.y = fmaf(a1.y, a1.y, s1.y);
        s1.z = fmaf(a1.z, a1.z, s1.z); s1.w = fmaf(a1.w, a1.w, s1.w);
        t1.x = fmaf(b1.x, b1.x, t1.x); t1.y = fmaf(b1.y, b1.y, t1.y);
        t1.z = fmaf(b1.z, b1.z, t1.z); t1.w = fmaf(b1.w, b1.w, t1.w);
    }

    // Coalesced partial stores (fully overwritten each launch -> no memset).
    const int p0 = b * HW4 + tid;            // j=0 position-group
    const int p1 = p0 + 512;                 // j=1
    wsp[(ch * 3 + 0) * NP4 + p0] = n0;
    wsp[(ch * 3 + 1) * NP4 + p0] = s0;
    wsp[(ch * 3 + 2) * NP4 + p0] = t0;
    wsp[(ch * 3 + 0) * NP4 + p1] = n1;
    wsp[(ch * 3 + 1) * NP4 + p1] = s1;
    wsp[(ch * 3 + 2) * NP4 + p1] = t1;
}

// ---------------- Phase B: combine chunks, cosine, masked mean ------------
__global__ __launch_bounds__(THR_B) void
combine_kernel(const float4* __restrict__ wsp,
               const int4*   __restrict__ mask4,
               double*       __restrict__ tail,
               float*        __restrict__ out)
{
    const int p4 = blockIdx.x * THR_B + threadIdx.x;   // [0, NP4)

    float4 fn = make_float4(0.f,0.f,0.f,0.f);
    float4 fu = fn, fm = fn;
#pragma unroll 4
    for (int ch = 0; ch < NCH; ++ch) {
        const float4 a = wsp[(ch * 3 + 0) * NP4 + p4];
        const float4 b = wsp[(ch * 3 + 1) * NP4 + p4];
        const float4 c = wsp[(ch * 3 + 2) * NP4 + p4];
        fn.x += a.x; fn.y += a.y; fn.z += a.z; fn.w += a.w;
        fu.x += b.x; fu.y += b.y; fu.z += b.z; fu.w += b.w;
        fm.x += c.x; fm.y += c.y; fm.z += c.z; fm.w += c.w;
    }

    const int4 mk = mask4[p4];
    double sd = 0.0, md = 0.0;
    {
        const float d0 = fmaxf(sqrtf(fu.x), SIM_EPS) * fmaxf(sqrtf(fm.x), SIM_EPS);
        const float d1 = fmaxf(sqrtf(fu.y), SIM_EPS) * fmaxf(sqrtf(fm.y), SIM_EPS);
        const float d2 = fmaxf(sqrtf(fu.z), SIM_EPS) * fmaxf(sqrtf(fm.z), SIM_EPS);
        const float d3 = fmaxf(sqrtf(fu.w), SIM_EPS) * fmaxf(sqrtf(fm.w), SIM_EPS);
        if (mk.x != 0) { sd += (double)(fn.x / d0); md += 1.0; }
        if (mk.y != 0) { sd += (double)(fn.y / d1); md += 1.0; }
        if (mk.z != 0) { sd += (double)(fn.z / d2); md += 1.0; }
        if (mk.w != 0) { sd += (double)(fn.w / d3); md += 1.0; }
    }

#pragma unroll
    for (int off = 32; off > 0; off >>= 1) {
        sd += __shfl_down(sd, off, 64);
        md += __shfl_down(md, off, 64);
    }

    __shared__ double rs[THR_B / 64];
    __shared__ double rm[THR_B / 64];
    const int wv = threadIdx.x >> 6;
    const int l  = threadIdx.x & 63;
    if (l == 0) { rs[wv] = sd; rm[wv] = md; }
    __syncthreads();

    if (threadIdx.x == 0) {
        double ts = 0.0, tm = 0.0;
#pragma unroll
        for (int k = 0; k < THR_B / 64; ++k) { ts += rs[k]; tm += rm[k]; }
        atomicAdd(&tail[0], ts);
        atomicAdd(&tail[1], tm);
        __threadfence();
        const unsigned long long prev =
            atomicAdd((unsigned long long*)&tail[2], 1ull);
        if (prev == (unsigned long long)(NBLK_B - 1)) {
            const double s  = atomicAdd(&tail[0], 0.0);
            const double mc = atomicAdd(&tail[1], 0.0);
            out[0] = (float)(s / mc);
        }
    }
}

// ---------------- Fallback (small ws): proven v2 geometry + ticket --------
__global__ __launch_bounds__(512) void
fallback_kernel(const float4* __restrict__ u4,
                const float4* __restrict__ m4,
                const int*    __restrict__ mask,
                double*       __restrict__ ws,
                float*        __restrict__ out)
{
    __shared__ float4 s_num[8][64];
    __shared__ float4 s_uu [8][64];
    __shared__ float4 s_mm [8][64];

    const int wv = threadIdx.x >> 6;
    const int l  = threadIdx.x & 63;
    const int pos0 = blockIdx.x * 256;
    const int b    = pos0 >> 12;
    const int hw0  = pos0 & (HWSZ - 1);

    const size_t base4 = (size_t)b * CC * HW4 + (size_t)(wv * 32) * HW4
                       + (size_t)(hw0 >> 2) + (size_t)l;
    const float4* __restrict__ up = u4 + base4;
    const float4* __restrict__ mp = m4 + base4;

    float4 num = make_float4(0.f,0.f,0.f,0.f), uu = num, mm = num;
#pragma unroll 4
    for (int c = 0; c < 32; ++c) {
        const float4 a  = up[(size_t)c * HW4];
        const float4 bv = mp[(size_t)c * HW4];
        num.x = fmaf(a.x, bv.x, num.x); num.y = fmaf(a.y, bv.y, num.y);
        num.z = fmaf(a.z, bv.z, num.z); num.w = fmaf(a.w, bv.w, num.w);
        uu.x  = fmaf(a.x, a.x, uu.x);   uu.y  = fmaf(a.y, a.y, uu.y);
        uu.z  = fmaf(a.z, a.z, uu.z);   uu.w  = fmaf(a.w, a.w, uu.w);
        mm.x  = fmaf(bv.x, bv.x, mm.x); mm.y  = fmaf(bv.y, bv.y, mm.y);
        mm.z  = fmaf(bv.z, bv.z, mm.z); mm.w  = fmaf(bv.w, bv.w, mm.w);
    }
    s_num[wv][l] = num; s_uu[wv][l] = uu; s_mm[wv][l] = mm;
    __syncthreads();

    double sd = 0.0, md = 0.0;
    if (threadIdx.x < 256) {
        const int t = threadIdx.x;
        float fn = 0.f, fu = 0.f, fm = 0.f;
#pragma unroll
        for (int k = 0; k < 8; ++k) {
            fn += ((const float*)s_num[k])[t];
            fu += ((const float*)s_uu [k])[t];
            fm += ((const float*)s_mm [k])[t];
        }
        const float denom = fmaxf(sqrtf(fu), SIM_EPS) * fmaxf(sqrtf(fm), SIM_EPS);
        if (mask[pos0 + t] != 0) { sd = (double)(fn / denom); md = 1.0; }
    }
#pragma unroll
    for (int off = 32; off > 0; off >>= 1) {
        sd += __shfl_down(sd, off, 64);
        md += __shfl_down(md, off, 64);
    }
    __shared__ double rs[8], rm[8];
    if (l == 0) { rs[wv] = sd; rm[wv] = md; }
    __syncthreads();
    if (threadIdx.x == 0) {
        double ts = 0.0, tm = 0.0;
#pragma unroll
        for (int k = 0; k < 8; ++k) { ts += rs[k]; tm += rm[k]; }
        atomicAdd(&ws[0], ts);
        atomicAdd(&ws[1], tm);
        __threadfence();
        const unsigned long long prev =
            atomicAdd((unsigned long long*)&ws[2], 1ull);
        if (prev == (unsigned long long)((NPOS / 256) - 1)) {
            const double s  = atomicAdd(&ws[0], 0.0);
            const double mc = atomicAdd(&ws[1], 0.0);
            out[0] = (float)(s / mc);
        }
    }
}

extern "C" void kernel_launch(void* const* d_in, const int* in_sizes, int n_in,
                              void* d_out, int out_size, void* d_ws, size_t ws_size,
                              hipStream_t stream)
{
    const float4* u4   = (const float4*)d_in[0];
    const float4* m4   = (const float4*)d_in[1];
    const int*    mask = (const int*)d_in[2];
    float* out = (float*)d_out;

    if (ws_size >= WS_NEED) {
        double* tail = (double*)((char*)d_ws + (size_t)WS_PART_F4 * 16);
        // Only the tail needs zeroing (partials are fully overwritten).
        hipMemsetAsync(tail, 0, 64, stream);
        partial_kernel<<<NBLK_A, THR_A, 0, stream>>>(u4, m4, (float4*)d_ws);
        combine_kernel<<<NBLK_B, THR_B, 0, stream>>>((const float4*)d_ws,
                                                     (const int4*)mask, tail, out);
    } else {
        hipMemsetAsync(d_ws, 0, 3 * sizeof(double), stream);
        fallback_kernel<<<NPOS / 256, 512, 0, stream>>>(u4, m4, mask,
                                                        (double*)d_ws, out);
    }
}